// Round 1
// baseline (517.447 us; speedup 1.0000x reference)
//
#include <hip/hip_runtime.h>

// E3NNLifting: out[n, i] = x[n, i%3] * w1[i/3]   for i in [0,126)
//              out[n, 126+m] = x[n, 3] * w0[m]   for m in {0,1}
// N = 1e6 rows, 128 f32 outputs per row. Memory-bound (512 MB writes).
//
// Layout: 32 lanes per row; lane t writes float4 covering outputs [4t, 4t+4).
// Each output is a dot product of the x-row (4 floats) with a per-(t,j)
// coefficient vector that is row-independent -> hoisted before the row loop.

__global__ __launch_bounds__(256) void e3nn_lift_kernel(
    const float* __restrict__ x, const float* __restrict__ w1,
    const float* __restrict__ w0, float* __restrict__ out, int n)
{
    const int tid = blockIdx.x * blockDim.x + threadIdx.x;
    const int t = tid & 31;              // which float4 of the 128-float row
    const int row0 = tid >> 5;
    const int rowStride = (gridDim.x * blockDim.x) >> 5;

    // Per-thread coefficients: out4[j] = x0*a0[j] + x1*a1[j] + x2*a2[j] + x3*a3[j]
    // Static j indexing via unroll -> stays in registers (rule #20).
    float a0[4], a1[4], a2[4], a3[4];
#pragma unroll
    for (int j = 0; j < 4; ++j) {
        const int i = 4 * t + j;
        float c0 = 0.f, c1 = 0.f, c2 = 0.f, c3 = 0.f;
        if (i < 126) {
            const int q = i / 3;         // w1 index
            const int r = i - q * 3;     // x component 0..2
            const float w = w1[q];       // tiny table, L1-cached broadcast
            c0 = (r == 0) ? w : 0.f;
            c1 = (r == 1) ? w : 0.f;
            c2 = (r == 2) ? w : 0.f;
        } else {
            c3 = w0[i - 126];
        }
        a0[j] = c0; a1[j] = c1; a2[j] = c2; a3[j] = c3;
    }

    const float4* __restrict__ x4 = (const float4*)x;
    float4* __restrict__ out4 = (float4*)out;

    for (int row = row0; row < n; row += rowStride) {
        const float4 xr = x4[row];       // 32 lanes same addr -> broadcast
        float o[4];
#pragma unroll
        for (int j = 0; j < 4; ++j) {
            o[j] = xr.x * a0[j] + xr.y * a1[j] + xr.z * a2[j] + xr.w * a3[j];
        }
        float4 ov = make_float4(o[0], o[1], o[2], o[3]);
        out4[(size_t)row * 32 + t] = ov;  // wave writes 2 contiguous rows (1 KiB)
    }
}

extern "C" void kernel_launch(void* const* d_in, const int* in_sizes, int n_in,
                              void* d_out, int out_size, void* d_ws, size_t ws_size,
                              hipStream_t stream) {
    const float* x  = (const float*)d_in[0];   // (N,4) f32
    const float* w1 = (const float*)d_in[1];   // (42,) f32
    const float* w0 = (const float*)d_in[2];   // (2,)  f32
    float* out = (float*)d_out;                // (N,128) f32

    const int n = in_sizes[0] / 4;             // N rows

    const int block = 256;
    const int grid = 2048;                     // grid-stride, ~8 blocks/CU
    hipLaunchKernelGGL(e3nn_lift_kernel, dim3(grid), dim3(block), 0, stream,
                       x, w1, w0, out, n);
}